// Round 5
// baseline (181.869 us; speedup 1.0000x reference)
//
#include <hip/hip_runtime.h>
#include <stdint.h>

// GRU: B=4096, T=128, I=16, H=64. Gate order r,z,n (PyTorch).
// v4: RB=8, 512 blocks -> 2 INDEPENDENT blocks/CU (cross-block latency
// hiding; v3 showed same-block waves phase-lock at barriers and can't fill
// stalls). v2 single-phase structure: 4 waves x 256 thr, wave owns 16 hidden
// cols x all 3 gates, full K (21-22 MFMAs), 1 barrier/step. Gate cells
// (8 rows x 64 cols) redistributed so all 64 lanes finalize 2 cells each via
// shfl_xor(32) + select (no idle lane-groups, no LDS exchange). Split-bf16
// (hi*hi+lo*hi+hi*lo) recurrence; exp2 scales pre-folded into weights;
// biases in MFMA C-init. h rows 8..15 of the M=16 tile stay zero (unused).

#define T_STEPS 128
#define NI 16
#define NH 64
#define RB 8

typedef float    f32x4  __attribute__((ext_vector_type(4)));
typedef uint32_t u32x4  __attribute__((ext_vector_type(4)));
typedef short    bf16x8 __attribute__((ext_vector_type(8)));  // MFMA operand
typedef __bf16   bfv8   __attribute__((ext_vector_type(8)));

static constexpr float LOG2E = 1.4426950408889634f;

static __device__ __forceinline__ uint32_t fbits(float f) { return __builtin_bit_cast(uint32_t, f); }
static __device__ __forceinline__ float    bitsf(uint32_t u) { return __builtin_bit_cast(float, u); }

// byte offset inside a [16 rows][64 cols] bf16 region (128B rows),
// 16B-chunk XOR swizzle by row so strided frag reads are 2-way (free).
static __device__ __forceinline__ int h_addr(int row, int col) {
  return row * 128 + (((col >> 3) ^ (row & 7)) << 4) + ((col & 7) << 1);
}

static __device__ __forceinline__ bf16x8 ld_frag16(const unsigned char* p) {
  u32x4 v = *(const u32x4*)p;                           // ds_read_b128
  return __builtin_bit_cast(bf16x8, v);
}

#define MFMA(acc, a, b) acc = __builtin_amdgcn_mfma_f32_16x16x32_bf16(a, b, acc, 0, 0, 0)

__global__ __launch_bounds__(256)
void gru_fused(const float* __restrict__ x,
               const float* __restrict__ w_ih,
               const float* __restrict__ w_hh,
               const float* __restrict__ b_ih,
               const float* __restrict__ b_hh,
               const float* __restrict__ fc_w,
               const float* __restrict__ fc_b,
               float* __restrict__ out)
{
  __shared__ __align__(16) unsigned char sH[2][2048];   // [hi/lo][16x64 bf16]
  __shared__ float s_red[4][8];

  const int tid  = threadIdx.x;
  const int lane = tid & 63;
  const int wv   = tid >> 6;       // wave 0..3
  const int colg = lane & 15;      // A-row (batch row) / col within tile
  const int grp  = lane >> 4;      // lane group 0..3 (k-group)
  const int rb   = blockIdx.x * RB;
  const int hc   = wv * 16 + colg; // this lane's hidden-unit column (0..63)

  // zero whole h buffer (h0 = 0; rows 8..15 stay zero forever)
  {
    uint32_t* p = (uint32_t*)&sH[0][0];
    #pragma unroll
    for (int i = 0; i < 4; ++i) p[tid + 256 * i] = 0u;
  }

  // ---- weight B-fragments (registers, loaded once), pre-scaled ----
  // B-frag: lane holds B[k][n], n = lane&15 -> hc, k = grp*8 + j (B = w^T).
  const float scl0 = -LOG2E, scl2 = 2.0f * LOG2E;
  bf16x8 bhi[3][2], blo[3][2], bx[3];
  #pragma unroll
  for (int g = 0; g < 3; ++g) {
    const float s = (g == 2) ? scl2 : scl0;
    const float* wr = w_hh + (size_t)(g * 64 + hc) * NH + grp * 8;
    #pragma unroll
    for (int kt = 0; kt < 2; ++kt) {
      bfv8 vhi, vlo;
      #pragma unroll
      for (int j = 0; j < 8; ++j) {
        float w = wr[kt * 32 + j] * s;
        __bf16 hi = (__bf16)w;                 // RNE
        vhi[j] = hi;
        vlo[j] = (__bf16)(w - (float)hi);
      }
      bhi[g][kt] = __builtin_bit_cast(bf16x8, vhi);
      blo[g][kt] = __builtin_bit_cast(bf16x8, vlo);
    }
    // x K-tile: k<16 pairs with x_hi, k>=16 with x_lo; both halves use w_ih
    const float* wi = w_ih + (size_t)(g * 64 + hc) * NI + (grp & 1) * 8;
    bfv8 vx;
    #pragma unroll
    for (int j = 0; j < 8; ++j) vx[j] = (__bf16)(wi[j] * s);
    bx[g] = __builtin_bit_cast(bf16x8, vx);
  }

  // biases (pre-scaled) folded into accumulator init
  const float biasR  = scl0 * (b_ih[hc] + b_hh[hc]);
  const float biasZ  = scl0 * (b_ih[64 + hc] + b_hh[64 + hc]);
  const float biasNh = scl2 * b_hh[128 + hc];
  const float biasNx = scl2 * b_ih[128 + hc];

  // per-lane x pointer: batch row rb + (colg&7)  (rows 8..15 duplicate 0..7;
  // their acc rows are discarded — avoids OOB on the last block)
  const float* xp = x + (size_t)(rb + (colg & 7)) * T_STEPS * NI + (grp & 1) * 8;

  const int a_off0 = h_addr(colg, 0 * 32 + grp * 8);  // A-frag LDS offsets
  const int a_off1 = h_addr(colg, 1 * 32 + grp * 8);

  // gate-cell mapping: lane (grp,colg) finalizes rows row0, row0+1 at col hc
  // grp0->rows 0,1 (own q0,q1); grp1->4,5 (own); grp2->2,3 (partner q2,q3);
  // grp3->6,7 (partner q2,q3)   [partner = lane ^ 32]
  const int row0 = ((grp & 1) << 2) | ((grp >> 1) << 1);
  const int wo0  = h_addr(row0,     hc);
  const int wo1  = h_addr(row0 + 1, hc);
  const bool own_q01 = (lane < 32);

  float hold0 = 0.f, hold1 = 0.f;   // fp32 master h for this lane's 2 cells

  f32x4 xa = *(const f32x4*)(xp);   // prefetch t=0
  f32x4 xb = *(const f32x4*)(xp + 4);
  const bool hi_grp = (grp < 2);

  __syncthreads();

  for (int t = 0; t < T_STEPS; ++t) {
    // prefetch next step's x
    const int tn = (t < T_STEPS - 1) ? (t + 1) : t;
    f32x4 xna = *(const f32x4*)(xp + (size_t)tn * NI);
    f32x4 xnb = *(const f32x4*)(xp + (size_t)tn * NI + 4);

    // A-fragment ds_reads for current h (issue first)
    bf16x8 ah0 = ld_frag16((const unsigned char*)sH + a_off0);
    bf16x8 ah1 = ld_frag16((const unsigned char*)sH + a_off1);
    bf16x8 al0 = ld_frag16((const unsigned char*)sH + 2048 + a_off0);
    bf16x8 al1 = ld_frag16((const unsigned char*)sH + 2048 + a_off1);

    // build split-bf16 x fragment: grp 0,1 carry trunc-hi(x); 2,3 residual
    uint32_t d0, d1, d2, d3;
    {
      float v[8];
      #pragma unroll
      for (int j = 0; j < 4; ++j) {
        float x0 = xa[j], x1 = xb[j];
        float b0 = bitsf(fbits(x0) & 0xffff0000u);
        float b1 = bitsf(fbits(x1) & 0xffff0000u);
        v[j]     = hi_grp ? x0 : (x0 - b0);
        v[4 + j] = hi_grp ? x1 : (x1 - b1);
      }
      d0 = __builtin_amdgcn_perm(fbits(v[1]), fbits(v[0]), 0x07060302u);
      d1 = __builtin_amdgcn_perm(fbits(v[3]), fbits(v[2]), 0x07060302u);
      d2 = __builtin_amdgcn_perm(fbits(v[5]), fbits(v[4]), 0x07060302u);
      d3 = __builtin_amdgcn_perm(fbits(v[7]), fbits(v[6]), 0x07060302u);
    }
    u32x4 axu = {d0, d1, d2, d3};
    bf16x8 ax = __builtin_bit_cast(bf16x8, axu);

    f32x4 aR  = {biasR,  biasR,  biasR,  biasR};
    f32x4 aZ  = {biasZ,  biasZ,  biasZ,  biasZ};
    f32x4 aNh = {biasNh, biasNh, biasNh, biasNh};
    f32x4 aNx = {biasNx, biasNx, biasNx, biasNx};

    // split-bf16 h-GEMM + x tile
    MFMA(aR, ah0, bhi[0][0]); MFMA(aR, ah1, bhi[0][1]);
    MFMA(aR, al0, bhi[0][0]); MFMA(aR, al1, bhi[0][1]);
    MFMA(aR, ah0, blo[0][0]); MFMA(aR, ah1, blo[0][1]);
    MFMA(aR, ax, bx[0]);

    MFMA(aZ, ah0, bhi[1][0]); MFMA(aZ, ah1, bhi[1][1]);
    MFMA(aZ, al0, bhi[1][0]); MFMA(aZ, al1, bhi[1][1]);
    MFMA(aZ, ah0, blo[1][0]); MFMA(aZ, ah1, blo[1][1]);
    MFMA(aZ, ax, bx[1]);

    MFMA(aNh, ah0, bhi[2][0]); MFMA(aNh, ah1, bhi[2][1]);
    MFMA(aNh, al0, bhi[2][0]); MFMA(aNh, al1, bhi[2][1]);
    MFMA(aNh, ah0, blo[2][0]); MFMA(aNh, ah1, blo[2][1]);
    MFMA(aNx, ax, bx[2]);

    // redistribute: lanes >=32 take partner's q2,q3 (rows 2,3 / 6,7)
    float pR2  = __shfl_xor(aR[2],  32, 64), pR3  = __shfl_xor(aR[3],  32, 64);
    float pZ2  = __shfl_xor(aZ[2],  32, 64), pZ3  = __shfl_xor(aZ[3],  32, 64);
    float pH2  = __shfl_xor(aNh[2], 32, 64), pH3  = __shfl_xor(aNh[3], 32, 64);
    float pX2  = __shfl_xor(aNx[2], 32, 64), pX3  = __shfl_xor(aNx[3], 32, 64);
    float cR0  = own_q01 ? aR[0]  : pR2,  cR1  = own_q01 ? aR[1]  : pR3;
    float cZ0  = own_q01 ? aZ[0]  : pZ2,  cZ1  = own_q01 ? aZ[1]  : pZ3;
    float cH0  = own_q01 ? aNh[0] : pH2,  cH1  = own_q01 ? aNh[1] : pH3;
    float cX0  = own_q01 ? aNx[0] : pX2,  cX1  = own_q01 ? aNx[1] : pX3;

    // gates + h update for 2 cells; write bf16 hi/lo of h_new
    {
      float r = __builtin_amdgcn_rcpf(1.0f + __builtin_amdgcn_exp2f(cR0));
      float z = __builtin_amdgcn_rcpf(1.0f + __builtin_amdgcn_exp2f(cZ0));
      float tv = fmaf(r, cH0, cX0);
      float n = fmaf(-2.0f, __builtin_amdgcn_rcpf(__builtin_amdgcn_exp2f(tv) + 1.0f), 1.0f);
      float h = n + z * (hold0 - n);
      hold0 = h;
      uint32_t u = fbits(h);
      float hif = bitsf(u & 0xffff0000u);
      *(uint16_t*)((unsigned char*)sH + wo0)        = (uint16_t)(u >> 16);
      *(uint16_t*)((unsigned char*)sH + 2048 + wo0) = (uint16_t)(fbits(h - hif) >> 16);
    }
    {
      float r = __builtin_amdgcn_rcpf(1.0f + __builtin_amdgcn_exp2f(cR1));
      float z = __builtin_amdgcn_rcpf(1.0f + __builtin_amdgcn_exp2f(cZ1));
      float tv = fmaf(r, cH1, cX1);
      float n = fmaf(-2.0f, __builtin_amdgcn_rcpf(__builtin_amdgcn_exp2f(tv) + 1.0f), 1.0f);
      float h = n + z * (hold1 - n);
      hold1 = h;
      uint32_t u = fbits(h);
      float hif = bitsf(u & 0xffff0000u);
      *(uint16_t*)((unsigned char*)sH + wo1)        = (uint16_t)(u >> 16);
      *(uint16_t*)((unsigned char*)sH + 2048 + wo1) = (uint16_t)(fbits(h - hif) >> 16);
    }
    __syncthreads();   // h(t+1) visible to all waves
    xa = xna; xb = xnb;
  }

  // ---- head: out[b] = sum_col h[b][col]*fc_w[col] + fc_b ----
  float fw = fc_w[hc];
  float v0 = hold0 * fw, v1 = hold1 * fw;
  #pragma unroll
  for (int off = 1; off < 16; off <<= 1) {     // reduce over 16 cols in grp
    v0 += __shfl_xor(v0, off, 64);
    v1 += __shfl_xor(v1, off, 64);
  }
  if (colg == 0) {
    s_red[wv][row0]     = v0;
    s_red[wv][row0 + 1] = v1;
  }
  __syncthreads();
  if (tid < RB) {
    out[rb + tid] = s_red[0][tid] + s_red[1][tid] + s_red[2][tid] + s_red[3][tid]
                  + fc_b[0];
  }
}

extern "C" void kernel_launch(void* const* d_in, const int* in_sizes, int n_in,
                              void* d_out, int out_size, void* d_ws, size_t ws_size,
                              hipStream_t stream) {
  (void)in_sizes; (void)n_in; (void)d_ws; (void)ws_size;
  const float* x    = (const float*)d_in[0];
  const float* w_ih = (const float*)d_in[1];
  const float* w_hh = (const float*)d_in[2];
  const float* b_ih = (const float*)d_in[3];
  const float* b_hh = (const float*)d_in[4];
  const float* fc_w = (const float*)d_in[5];
  const float* fc_b = (const float*)d_in[6];
  float* out = (float*)d_out;
  const int nblocks = out_size / RB;  // 4096/8 = 512 blocks -> 2 per CU
  gru_fused<<<dim3(nblocks), dim3(256), 0, stream>>>(x, w_ih, w_hh, b_ih, b_hh,
                                                     fc_w, fc_b, out);
}

// Round 6
// 166.587 us; speedup vs baseline: 1.0917x; 1.0917x over previous
//
#include <hip/hip_runtime.h>
#include <stdint.h>

// GRU: B=4096, T=128, I=16, H=64. Gate order r,z,n (PyTorch).
// v5: SWAPPED-OPERAND form. gates[3H x 16batch] = W[3H x 64] @ h[64 x 16].
// A = W (registers, hi/lo split, scales pre-folded), B = h (LDS, hi/lo bf16)
// and x (per-lane regs, hi|lo packed K=32). C layout: row=hidden, col=batch
// => gates fully lane-local (no shfl redistribute, no idle lanes); each lane
// outputs 4 consecutive hidden units at one batch col => packed b64 writes,
// b128 reads, chunk-XOR swizzled. RB=16, 256 blocks (1/CU), 4 waves,
// 21 MFMAs/wave/step, 1 barrier/step. Split-bf16 3-term recurrence.

#define T_STEPS 128
#define NI 16
#define NH 64
#define RB 16
#define ROWB 272   // LDS bytes per batch column: 128B h_hi + 128B h_lo + 16B pad

typedef float    f32x4  __attribute__((ext_vector_type(4)));
typedef uint32_t u32x4  __attribute__((ext_vector_type(4)));
typedef uint32_t u32x2  __attribute__((ext_vector_type(2)));
typedef short    bf16x8 __attribute__((ext_vector_type(8)));  // MFMA operand
typedef __bf16   bfv8   __attribute__((ext_vector_type(8)));

static constexpr float LOG2E = 1.4426950408889634f;

static __device__ __forceinline__ uint32_t fbits(float f) { return __builtin_bit_cast(uint32_t, f); }
static __device__ __forceinline__ float    bitsf(uint32_t u) { return __builtin_bit_cast(float, u); }

static __device__ __forceinline__ bf16x8 ld_frag16(const unsigned char* p) {
  u32x4 v = *(const u32x4*)p;                           // ds_read_b128
  return __builtin_bit_cast(bf16x8, v);
}

// A-operand first, B second:
#define MFMA(A, B, C) __builtin_amdgcn_mfma_f32_16x16x32_bf16(A, B, C, 0, 0, 0)

__global__ __launch_bounds__(256)
void gru_fused(const float* __restrict__ x,
               const float* __restrict__ w_ih,
               const float* __restrict__ w_hh,
               const float* __restrict__ b_ih,
               const float* __restrict__ b_hh,
               const float* __restrict__ fc_w,
               const float* __restrict__ fc_b,
               float* __restrict__ out)
{
  __shared__ __align__(16) unsigned char sH[16 * ROWB];  // [batch col][hi|lo|pad]
  __shared__ float s_red[4][16];

  const int tid  = threadIdx.x;
  const int lane = tid & 63;
  const int wv   = tid >> 6;       // wave 0..3: owns hidden [16wv, 16wv+16)
  const int colg = lane & 15;      // batch column (B-frag n / C col)
  const int grp  = lane >> 4;      // k-group / C row-group
  const int rb   = blockIdx.x * RB;
  const int hc   = wv * 16 + colg; // used for W A-frag row indexing

  // zero h LDS (h0 = 0): 16*272 = 4352 B = 1088 dwords
  for (int i = tid; i < 1088; i += 256) ((uint32_t*)sH)[i] = 0u;

  // ---- W A-frags (registers, once), scales pre-folded ----
  // A-frag: lane (grp,colg) holds A[m=colg][k=kt*32+grp*8+j]
  // h-path: A[m][k] = w_hh[(g*64 + wv*16 + m)*64 + k] * scl_g, split hi/lo.
  const float scl0 = -LOG2E, scl2 = 2.0f * LOG2E;
  bf16x8 whi[3][2], wlo[3][2], axw[3];
  #pragma unroll
  for (int g = 0; g < 3; ++g) {
    const float s = (g == 2) ? scl2 : scl0;
    const float* wr = w_hh + (size_t)(g * 64 + hc) * NH + grp * 8;
    #pragma unroll
    for (int kt = 0; kt < 2; ++kt) {
      bfv8 vhi, vlo;
      #pragma unroll
      for (int j = 0; j < 8; ++j) {
        float w = wr[kt * 32 + j] * s;
        __bf16 hi = (__bf16)w;                 // RNE
        vhi[j] = hi;
        vlo[j] = (__bf16)(w - (float)hi);
      }
      whi[g][kt] = __builtin_bit_cast(bf16x8, vhi);
      wlo[g][kt] = __builtin_bit_cast(bf16x8, vlo);
    }
    // x-path A: k<16 pairs x_hi, k>=16 pairs x_lo; both halves = w_ih
    const float* wi = w_ih + (size_t)(g * 64 + hc) * NI + (grp & 1) * 8;
    bfv8 vx;
    #pragma unroll
    for (int j = 0; j < 8; ++j) vx[j] = (__bf16)(wi[j] * s);
    axw[g] = __builtin_bit_cast(bf16x8, vx);
  }

  // ---- per-reg biases (C-init vectors); reg q -> hidden wv*16 + grp*4 + q
  f32x4 bR4, bZ4, bNh4, bNx4;
  #pragma unroll
  for (int q = 0; q < 4; ++q) {
    const int hx = wv * 16 + grp * 4 + q;
    bR4[q]  = scl0 * (b_ih[hx] + b_hh[hx]);
    bZ4[q]  = scl0 * (b_ih[64 + hx] + b_hh[64 + hx]);
    bNh4[q] = scl2 * b_hh[128 + hx];
    bNx4[q] = scl2 * b_ih[128 + hx];
  }

  // ---- LDS addressing (t-invariant), 16B-chunk XOR swizzle by batch col ----
  const int swz = colg & 7;
  const int rd_hi0 = colg * ROWB + ((0 * 4 + grp) ^ swz) * 16;        // kt=0
  const int rd_hi1 = colg * ROWB + ((1 * 4 + grp) ^ swz) * 16;        // kt=1
  const int rd_lo0 = colg * ROWB + 128 + ((0 * 4 + grp) ^ swz) * 16;
  const int rd_lo1 = colg * ROWB + 128 + ((1 * 4 + grp) ^ swz) * 16;
  // writes: lane's 4 cells = hidden (wv*16+4grp)..+3 at batch colg -> 8B run
  const int wch   = (2 * wv + (grp >> 1)) ^ swz;
  const int wr_hi = colg * ROWB + wch * 16 + (grp & 1) * 8;
  const int wr_lo = wr_hi + 128;

  float hreg[4] = {0.f, 0.f, 0.f, 0.f};  // h[hidden wv*16+4grp+q][batch colg]

  // per-lane x pointer: batch row rb+colg, 8 floats at (grp&1)*8
  const float* xp = x + (size_t)(rb + colg) * T_STEPS * NI + (grp & 1) * 8;
  f32x4 xa = *(const f32x4*)(xp);
  f32x4 xb = *(const f32x4*)(xp + 4);
  const bool hi_grp = (grp < 2);

  __syncthreads();

  for (int t = 0; t < T_STEPS; ++t) {
    // h B-frags (issue LDS reads first)
    bf16x8 bh_hi0 = ld_frag16(sH + rd_hi0);
    bf16x8 bh_hi1 = ld_frag16(sH + rd_hi1);
    bf16x8 bh_lo0 = ld_frag16(sH + rd_lo0);
    bf16x8 bh_lo1 = ld_frag16(sH + rd_lo1);

    // x B-frag: grp 0,1 carry trunc-hi(x); grp 2,3 residual (proven pack)
    uint32_t d0, d1, d2, d3;
    {
      float v[8];
      #pragma unroll
      for (int j = 0; j < 4; ++j) {
        float x0 = xa[j], x1 = xb[j];
        float b0 = bitsf(fbits(x0) & 0xffff0000u);
        float b1 = bitsf(fbits(x1) & 0xffff0000u);
        v[j]     = hi_grp ? x0 : (x0 - b0);
        v[4 + j] = hi_grp ? x1 : (x1 - b1);
      }
      d0 = __builtin_amdgcn_perm(fbits(v[1]), fbits(v[0]), 0x07060302u);
      d1 = __builtin_amdgcn_perm(fbits(v[3]), fbits(v[2]), 0x07060302u);
      d2 = __builtin_amdgcn_perm(fbits(v[5]), fbits(v[4]), 0x07060302u);
      d3 = __builtin_amdgcn_perm(fbits(v[7]), fbits(v[6]), 0x07060302u);
    }
    u32x4 axu = {d0, d1, d2, d3};
    bf16x8 xfrag = __builtin_bit_cast(bf16x8, axu);

    // prefetch next step's x
    const int tn = (t < T_STEPS - 1) ? (t + 1) : t;
    f32x4 xna = *(const f32x4*)(xp + (size_t)tn * NI);
    f32x4 xnb = *(const f32x4*)(xp + (size_t)tn * NI + 4);

    // x-MFMAs first (independent of LDS reads), biases as C-in
    f32x4 aR  = MFMA(axw[0], xfrag, bR4);
    f32x4 aZ  = MFMA(axw[1], xfrag, bZ4);
    f32x4 aNx = MFMA(axw[2], xfrag, bNx4);

    // h-MFMAs: hi*hi + hi(W)*lo(h) + lo(W)*hi(h)
    aR = MFMA(whi[0][0], bh_hi0, aR); aR = MFMA(whi[0][1], bh_hi1, aR);
    aR = MFMA(whi[0][0], bh_lo0, aR); aR = MFMA(whi[0][1], bh_lo1, aR);
    aR = MFMA(wlo[0][0], bh_hi0, aR); aR = MFMA(wlo[0][1], bh_hi1, aR);

    aZ = MFMA(whi[1][0], bh_hi0, aZ); aZ = MFMA(whi[1][1], bh_hi1, aZ);
    aZ = MFMA(whi[1][0], bh_lo0, aZ); aZ = MFMA(whi[1][1], bh_lo1, aZ);
    aZ = MFMA(wlo[1][0], bh_hi0, aZ); aZ = MFMA(wlo[1][1], bh_hi1, aZ);

    f32x4 aNh = MFMA(whi[2][0], bh_hi0, bNh4);
    aNh = MFMA(whi[2][1], bh_hi1, aNh);
    aNh = MFMA(whi[2][0], bh_lo0, aNh); aNh = MFMA(whi[2][1], bh_lo1, aNh);
    aNh = MFMA(wlo[2][0], bh_hi0, aNh); aNh = MFMA(wlo[2][1], bh_hi1, aNh);

    // gates (lane-local, 4 cells: hidden wv*16+4grp+q, batch colg)
    float h0, h1, h2, h3;
    {
      float r = __builtin_amdgcn_rcpf(1.0f + __builtin_amdgcn_exp2f(aR[0]));
      float z = __builtin_amdgcn_rcpf(1.0f + __builtin_amdgcn_exp2f(aZ[0]));
      float n = fmaf(-2.0f, __builtin_amdgcn_rcpf(__builtin_amdgcn_exp2f(fmaf(r, aNh[0], aNx[0])) + 1.0f), 1.0f);
      h0 = n + z * (hreg[0] - n); hreg[0] = h0;
    }
    {
      float r = __builtin_amdgcn_rcpf(1.0f + __builtin_amdgcn_exp2f(aR[1]));
      float z = __builtin_amdgcn_rcpf(1.0f + __builtin_amdgcn_exp2f(aZ[1]));
      float n = fmaf(-2.0f, __builtin_amdgcn_rcpf(__builtin_amdgcn_exp2f(fmaf(r, aNh[1], aNx[1])) + 1.0f), 1.0f);
      h1 = n + z * (hreg[1] - n); hreg[1] = h1;
    }
    {
      float r = __builtin_amdgcn_rcpf(1.0f + __builtin_amdgcn_exp2f(aR[2]));
      float z = __builtin_amdgcn_rcpf(1.0f + __builtin_amdgcn_exp2f(aZ[2]));
      float n = fmaf(-2.0f, __builtin_amdgcn_rcpf(__builtin_amdgcn_exp2f(fmaf(r, aNh[2], aNx[2])) + 1.0f), 1.0f);
      h2 = n + z * (hreg[2] - n); hreg[2] = h2;
    }
    {
      float r = __builtin_amdgcn_rcpf(1.0f + __builtin_amdgcn_exp2f(aR[3]));
      float z = __builtin_amdgcn_rcpf(1.0f + __builtin_amdgcn_exp2f(aZ[3]));
      float n = fmaf(-2.0f, __builtin_amdgcn_rcpf(__builtin_amdgcn_exp2f(fmaf(r, aNh[3], aNx[3])) + 1.0f), 1.0f);
      h3 = n + z * (hreg[3] - n); hreg[3] = h3;
    }

    // pack hi (trunc) + lo (residual) and write: 2x ds_write_b64
    {
      uint32_t hi01 = __builtin_amdgcn_perm(fbits(h1), fbits(h0), 0x07060302u);
      uint32_t hi23 = __builtin_amdgcn_perm(fbits(h3), fbits(h2), 0x07060302u);
      float l0 = h0 - bitsf(fbits(h0) & 0xffff0000u);
      float l1 = h1 - bitsf(fbits(h1) & 0xffff0000u);
      float l2 = h2 - bitsf(fbits(h2) & 0xffff0000u);
      float l3 = h3 - bitsf(fbits(h3) & 0xffff0000u);
      uint32_t lo01 = __builtin_amdgcn_perm(fbits(l1), fbits(l0), 0x07060302u);
      uint32_t lo23 = __builtin_amdgcn_perm(fbits(l3), fbits(l2), 0x07060302u);
      u32x2 whiv = {hi01, hi23};
      u32x2 wlov = {lo01, lo23};
      *(u32x2*)(sH + wr_hi) = whiv;
      *(u32x2*)(sH + wr_lo) = wlov;
    }
    __syncthreads();   // h(t+1) visible to all waves
    xa = xna; xb = xnb;
  }

  // ---- head: out[b=rb+colg] = sum_hidden h[hid][b]*fc_w[hid] + fc_b ----
  float s;
  {
    const int hx = wv * 16 + grp * 4;
    s = hreg[0] * fc_w[hx] + hreg[1] * fc_w[hx + 1]
      + hreg[2] * fc_w[hx + 2] + hreg[3] * fc_w[hx + 3];
  }
  s += __shfl_xor(s, 16, 64);
  s += __shfl_xor(s, 32, 64);       // sum over the 4 k-groups at fixed colg
  if (lane < 16) s_red[wv][lane] = s;
  __syncthreads();
  if (tid < 16) {
    out[rb + tid] = s_red[0][tid] + s_red[1][tid] + s_red[2][tid] + s_red[3][tid]
                  + fc_b[0];
  }
}

extern "C" void kernel_launch(void* const* d_in, const int* in_sizes, int n_in,
                              void* d_out, int out_size, void* d_ws, size_t ws_size,
                              hipStream_t stream) {
  (void)in_sizes; (void)n_in; (void)d_ws; (void)ws_size;
  const float* x    = (const float*)d_in[0];
  const float* w_ih = (const float*)d_in[1];
  const float* w_hh = (const float*)d_in[2];
  const float* b_ih = (const float*)d_in[3];
  const float* b_hh = (const float*)d_in[4];
  const float* fc_w = (const float*)d_in[5];
  const float* fc_b = (const float*)d_in[6];
  float* out = (float*)d_out;
  const int nblocks = out_size / RB;  // 4096/16 = 256 blocks, 1 per CU
  gru_fused<<<dim3(nblocks), dim3(256), 0, stream>>>(x, w_ih, w_hh, b_ih, b_hh,
                                                     fc_w, fc_b, out);
}